// Round 1
// baseline (505.051 us; speedup 1.0000x reference)
//
#include <hip/hip_runtime.h>
#include <hip/hip_bf16.h>
#include <stdint.h>

// Problem constants (fixed by reference):
#define BB 8192      // batch
#define DD 512       // feature dim
#define NNEG 8       // NUM_NEG_CANDIDATES
#define HARDK 3      // HARD_NEG_K
// TEMPERATURE = 0.5 -> multiply logits by 2.0

// ---------------- threefry2x32 (exact JAX key schedule) ----------------
// JAX rotations: groups [13,15,26,6] / [17,29,16,24], 5 groups, key injections
// after each group with counter i+1. Verified against jax/_src/prng.py.
#define TF_RND(x0, x1, R) { x0 += x1; x1 = (x1 << R) | (x1 >> (32 - R)); x1 ^= x0; }

__host__ __device__ __forceinline__ void threefry2x32(uint32_t k0, uint32_t k1,
                                                      uint32_t x0, uint32_t x1,
                                                      uint32_t& o0, uint32_t& o1) {
  uint32_t ks2 = k0 ^ k1 ^ 0x1BD11BDAu;
  x0 += k0; x1 += k1;
  TF_RND(x0, x1, 13) TF_RND(x0, x1, 15) TF_RND(x0, x1, 26) TF_RND(x0, x1, 6)
  x0 += k1; x1 += ks2 + 1u;
  TF_RND(x0, x1, 17) TF_RND(x0, x1, 29) TF_RND(x0, x1, 16) TF_RND(x0, x1, 24)
  x0 += ks2; x1 += k0 + 2u;
  TF_RND(x0, x1, 13) TF_RND(x0, x1, 15) TF_RND(x0, x1, 26) TF_RND(x0, x1, 6)
  x0 += k0; x1 += k1 + 3u;
  TF_RND(x0, x1, 17) TF_RND(x0, x1, 29) TF_RND(x0, x1, 16) TF_RND(x0, x1, 24)
  x0 += k1; x1 += ks2 + 4u;
  TF_RND(x0, x1, 13) TF_RND(x0, x1, 15) TF_RND(x0, x1, 26) TF_RND(x0, x1, 6)
  x0 += ks2; x1 += k0 + 5u;
  o0 = x0; o1 = x1;
}

// ---------------- kernel 1: inverse row norms ----------------
__global__ __launch_bounds__(256) void norm_kernel(const float* __restrict__ feat,
                                                   float* __restrict__ inv_norm) {
  int wave = threadIdx.x >> 6, lane = threadIdx.x & 63;
  int row = blockIdx.x * 4 + wave;
  const float* fr = feat + (size_t)row * DD;
  float s = 0.0f;
  #pragma unroll
  for (int k = 0; k < DD / 64; ++k) {
    float x = fr[lane + 64 * k];
    s = fmaf(x, x, s);
  }
  #pragma unroll
  for (int d = 1; d < 64; d <<= 1) s += __shfl_xor(s, d, 64);
  if (lane == 0) inv_norm[row] = 1.0f / fmaxf(sqrtf(s), 1e-12f);
}

// ---------------- kernel 2: positive argmax + negative top-8 ----------------
// Per element (i,j): flat idx = i*8192+j. Partitionable path:
//   bits = o0 ^ o1 of threefry(key, hi=0, lo=idx), key = kp if same-label else kn.
// Selection key packs (bits>>9) with (8191-j) so u64 max == (value desc, index asc).
__device__ __forceinline__ unsigned long long u64max(unsigned long long a, unsigned long long b) {
  return a > b ? a : b;
}
#define CE_DESC(m, x, y) { if (m[x] < m[y]) { unsigned long long _t = m[x]; m[x] = m[y]; m[y] = _t; } }

__global__ __launch_bounds__(256) void select_kernel(const int* __restrict__ labels,
                                                     uint32_t kp0, uint32_t kp1,
                                                     uint32_t kn0, uint32_t kn1,
                                                     int* __restrict__ pos_j,
                                                     int* __restrict__ neg_idx) {
  int wave = threadIdx.x >> 6, lane = threadIdx.x & 63;
  int i = blockIdx.x * 4 + wave;
  int li = labels[i];
  unsigned long long best = 0ull;
  unsigned long long top[8] = {0ull,0ull,0ull,0ull,0ull,0ull,0ull,0ull};

  uint32_t rowbase = (uint32_t)i * (uint32_t)BB;
  for (int j = lane; j < BB; j += 64) {
    int lj = labels[j];
    bool same = (lj == li);
    // key select per-lane (branchless; avoids executing threefry twice per wave)
    uint32_t k0 = same ? kp0 : kn0;
    uint32_t k1 = same ? kp1 : kn1;
    uint32_t o0, o1;
    threefry2x32(k0, k1, 0u, rowbase + (uint32_t)j, o0, o1);
    uint32_t v = (o0 ^ o1) >> 9;  // the 23 mantissa bits that order the uniform/gumbel
    unsigned long long key = ((unsigned long long)v << 13) | (unsigned)(8191 - j);
    if (same) {
      if (j != i) best = u64max(best, key);
    } else {
      if (key > top[7]) {
        top[7] = key;
        #pragma unroll
        for (int s = 7; s > 0; --s) {
          if (top[s] > top[s - 1]) {
            unsigned long long t = top[s - 1]; top[s - 1] = top[s]; top[s] = t;
          }
        }
      }
    }
  }

  // wave-level reduce: argmax for positive
  #pragma unroll
  for (int d = 1; d < 64; d <<= 1) {
    unsigned long long o = __shfl_xor(best, d, 64);
    best = u64max(best, o);
  }
  // wave-level top-8 merge: butterfly, bitonic merge of two sorted-desc 8-lists
  #pragma unroll
  for (int d = 1; d < 64; d <<= 1) {
    unsigned long long o[8];
    #pragma unroll
    for (int r = 0; r < 8; ++r) o[r] = __shfl_xor(top[r], d, 64);
    unsigned long long m[8];
    #pragma unroll
    for (int r = 0; r < 8; ++r) m[r] = u64max(top[r], o[7 - r]);  // top-8 of union (bitonic)
    CE_DESC(m, 0, 4) CE_DESC(m, 1, 5) CE_DESC(m, 2, 6) CE_DESC(m, 3, 7)
    CE_DESC(m, 0, 2) CE_DESC(m, 1, 3) CE_DESC(m, 4, 6) CE_DESC(m, 5, 7)
    CE_DESC(m, 0, 1) CE_DESC(m, 2, 3) CE_DESC(m, 4, 5) CE_DESC(m, 6, 7)
    #pragma unroll
    for (int r = 0; r < 8; ++r) top[r] = m[r];
  }

  if (lane == 0) {
    // all-masked row -> JAX argmax returns 0
    pos_j[i] = best ? (8191 - (int)(best & 0x1FFFull)) : 0;
    #pragma unroll
    for (int r = 0; r < 8; ++r) neg_idx[i * 8 + r] = 8191 - (int)(top[r] & 0x1FFFull);
  }
}

// ---------------- kernel 3: 9 dots + logsumexp + mean ----------------
__global__ __launch_bounds__(256) void loss_kernel(const float* __restrict__ feat,
                                                   const float* __restrict__ inv_norm,
                                                   const int* __restrict__ pos_j,
                                                   const int* __restrict__ neg_idx,
                                                   float* __restrict__ out) {
  int wave = threadIdx.x >> 6, lane = threadIdx.x & 63;
  int i = blockIdx.x * 4 + wave;
  const float* fi = feat + (size_t)i * DD;
  float a[DD / 64];
  #pragma unroll
  for (int k = 0; k < DD / 64; ++k) a[k] = fi[lane + 64 * k];

  int cand[9];
  cand[0] = pos_j[i];
  #pragma unroll
  for (int m = 0; m < NNEG; ++m) cand[m + 1] = neg_idx[i * 8 + m];

  float dots[9];
  #pragma unroll
  for (int c = 0; c < 9; ++c) {
    const float* fc = feat + (size_t)cand[c] * DD;
    float s = 0.0f;
    #pragma unroll
    for (int k = 0; k < DD / 64; ++k) s = fmaf(a[k], fc[lane + 64 * k], s);
    #pragma unroll
    for (int d = 1; d < 64; d <<= 1) s += __shfl_xor(s, d, 64);
    dots[c] = s;
  }

  if (lane == 0) {
    float inv_i = inv_norm[i];
    float pos = dots[0] * inv_i * inv_norm[cand[0]] * 2.0f;  // /TEMPERATURE
    float t1 = -1e30f, t2 = -1e30f, t3 = -1e30f;             // top-3 of 8 negatives
    #pragma unroll
    for (int m = 0; m < NNEG; ++m) {
      float v = dots[m + 1] * inv_i * inv_norm[cand[m + 1]] * 2.0f;
      if (v > t1)      { t3 = t2; t2 = t1; t1 = v; }
      else if (v > t2) { t3 = t2; t2 = v; }
      else if (v > t3) { t3 = v; }
    }
    float mx = fmaxf(fmaxf(pos, t1), fmaxf(t2, t3));
    float lse = mx + logf(__expf(pos - mx) + __expf(t1 - mx) + __expf(t2 - mx) + __expf(t3 - mx));
    atomicAdd(out, (lse - pos) * (1.0f / (float)BB));
  }
}

// ---------------- launch ----------------
extern "C" void kernel_launch(void* const* d_in, const int* in_sizes, int n_in,
                              void* d_out, int out_size, void* d_ws, size_t ws_size,
                              hipStream_t stream) {
  const float* features = (const float*)d_in[0];
  const int* labels = (const int*)d_in[1];
  float* out = (float*)d_out;

  // workspace: inv_norm[8192] | pos_j[8192] | neg_idx[8192*8]  (~320 KB)
  float* inv_norm = (float*)d_ws;
  int* pos_j = (int*)((char*)d_ws + BB * sizeof(float));
  int* neg_idx = pos_j + BB;

  // JAX partitionable split of key(42) = (0,42):
  //   kp = threefry(key, 0, 0) as (o0,o1); kn = threefry(key, 0, 1).
  uint32_t kp0, kp1, kn0, kn1;
  threefry2x32(0u, 42u, 0u, 0u, kp0, kp1);
  threefry2x32(0u, 42u, 0u, 1u, kn0, kn1);

  hipMemsetAsync(d_out, 0, sizeof(float), stream);
  norm_kernel<<<BB / 4, 256, 0, stream>>>(features, inv_norm);
  select_kernel<<<BB / 4, 256, 0, stream>>>(labels, kp0, kp1, kn0, kn1, pos_j, neg_idx);
  loss_kernel<<<BB / 4, 256, 0, stream>>>(features, inv_norm, pos_j, neg_idx, out);
}

// Round 2
// 374.027 us; speedup vs baseline: 1.3503x; 1.3503x over previous
//
#include <hip/hip_runtime.h>
#include <hip/hip_bf16.h>
#include <stdint.h>

// Problem constants (fixed by reference):
#define BB 8192      // batch
#define DD 512       // feature dim
#define NNEG 8       // NUM_NEG_CANDIDATES
#define HARDK 3      // HARD_NEG_K
#define CAP 512      // per-wave candidate buffer (expected ~40 survivors)
// TEMPERATURE = 0.5 -> multiply logits by 2.0

// Threshold on the 23-bit uniform mantissa: keep top ~40 expected of ~8064
// negatives. 8388608 - 41984 -> E[count] = 8064*41984/2^23 ~= 40.4.
// P(count < 8) ~ Poisson(40) tail ~ 1e-11/row; exact fallback below anyway.
#define VT0 8346624u

__host__ __device__ __forceinline__ uint32_t rotl32(uint32_t x, int r) {
#if defined(__HIP_DEVICE_COMPILE__)
  return __builtin_amdgcn_alignbit(x, x, 32 - r);  // guaranteed v_alignbit_b32
#else
  return (x << r) | (x >> (32 - r));
#endif
}

// ---------------- threefry2x32 (exact JAX key schedule) ----------------
#define TF_RND(x0, x1, R) { x0 += x1; x1 = rotl32(x1, R); x1 ^= x0; }

__host__ __device__ __forceinline__ void threefry2x32(uint32_t k0, uint32_t k1,
                                                      uint32_t x0, uint32_t x1,
                                                      uint32_t& o0, uint32_t& o1) {
  uint32_t ks2 = k0 ^ k1 ^ 0x1BD11BDAu;
  x0 += k0; x1 += k1;
  TF_RND(x0, x1, 13) TF_RND(x0, x1, 15) TF_RND(x0, x1, 26) TF_RND(x0, x1, 6)
  x0 += k1; x1 += ks2 + 1u;
  TF_RND(x0, x1, 17) TF_RND(x0, x1, 29) TF_RND(x0, x1, 16) TF_RND(x0, x1, 24)
  x0 += ks2; x1 += k0 + 2u;
  TF_RND(x0, x1, 13) TF_RND(x0, x1, 15) TF_RND(x0, x1, 26) TF_RND(x0, x1, 6)
  x0 += k0; x1 += k1 + 3u;
  TF_RND(x0, x1, 17) TF_RND(x0, x1, 29) TF_RND(x0, x1, 16) TF_RND(x0, x1, 24)
  x0 += k1; x1 += ks2 + 4u;
  TF_RND(x0, x1, 13) TF_RND(x0, x1, 15) TF_RND(x0, x1, 26) TF_RND(x0, x1, 6)
  x0 += ks2; x1 += k0 + 5u;
  o0 = x0; o1 = x1;
}

// ---------------- kernel 1: inverse row norms ----------------
__global__ __launch_bounds__(256) void norm_kernel(const float* __restrict__ feat,
                                                   float* __restrict__ inv_norm) {
  int wave = threadIdx.x >> 6, lane = threadIdx.x & 63;
  int row = blockIdx.x * 4 + wave;
  const float4* fr = (const float4*)(feat + (size_t)row * DD);
  float4 a = fr[lane], b = fr[lane + 64];
  float s = a.x * a.x + a.y * a.y + a.z * a.z + a.w * a.w
          + b.x * b.x + b.y * b.y + b.z * b.z + b.w * b.w;
  #pragma unroll
  for (int d = 1; d < 64; d <<= 1) s += __shfl_xor(s, d, 64);
  if (lane == 0) inv_norm[row] = 1.0f / fmaxf(sqrtf(s), 1e-12f);
}

// ---------------- kernel 2: positive argmax + negative top-8 ----------------
// Packed selection key: ((v << 13) | (8191 - j)) + 1, so plain u64 max
// implements (value desc, index asc) with 0 as an empty sentinel.
__device__ __forceinline__ unsigned long long u64max(unsigned long long a, unsigned long long b) {
  return a > b ? a : b;
}
#define CE_DESC(m, x, y) { if (m[x] < m[y]) { unsigned long long _t = m[x]; m[x] = m[y]; m[y] = _t; } }

__global__ __launch_bounds__(256) void select_kernel(const int* __restrict__ labels,
                                                     uint32_t kp0, uint32_t kp1,
                                                     uint32_t kn0, uint32_t kn1,
                                                     int* __restrict__ pos_j,
                                                     int* __restrict__ neg_idx) {
  __shared__ unsigned long long buf[4][CAP];   // per-wave candidate buffers (16 KB)
  int wave = threadIdx.x >> 6, lane = threadIdx.x & 63;
  int i = blockIdx.x * 4 + wave;
  int li = labels[i];
  uint32_t rowbase = (uint32_t)i * (uint32_t)BB;
  unsigned long long best = 0ull;   // positive argmax key
  int count = 0;                    // wave-uniform candidate count

  // ---- main scan: 1 threefry per element, threshold-filtered append ----
  #pragma unroll 2
  for (int j = lane; j < BB; j += 64) {
    bool same = (labels[j] == li);
    uint32_t k0 = same ? kp0 : kn0;
    uint32_t k1 = same ? kp1 : kn1;
    uint32_t o0, o1;
    threefry2x32(k0, k1, 0u, rowbase + (uint32_t)j, o0, o1);
    uint32_t v = (o0 ^ o1) >> 9;  // 23 mantissa bits: monotone with the gumbel value
    unsigned long long key = (((unsigned long long)v << 13) | (unsigned)(8191 - j)) + 1ull;
    // positive: branchless running max
    unsigned long long pk = (same && (j != i)) ? key : 0ull;
    best = u64max(best, pk);
    // negative: rare threshold-passing append (ballot-indexed, no atomics)
    bool cand = (!same) && (v >= VT0);
    unsigned long long m = __ballot(cand);
    if (m) {
      if (cand) {
        int ofs = __builtin_amdgcn_mbcnt_hi((uint32_t)(m >> 32),
                   __builtin_amdgcn_mbcnt_lo((uint32_t)m, 0));
        int p = count + ofs;
        if (p < CAP) buf[wave][p] = key;
      }
      count += __popcll(m);
    }
  }

  // ---- exact fallback: widen window until >= 8 candidates (never taken
  // for this input: P ~ 1e-11/row, but keeps the kernel input-exact) ----
  uint32_t lo = VT0;
  while (count < 8 && lo > 0u) {
    uint32_t W = 8388608u - lo;
    uint32_t newlo = (W >= 1048576u) ? 0u : (8388608u - W * 8u);
    for (int j = lane; j < BB; j += 64) {
      bool same = (labels[j] == li);
      uint32_t o0, o1;
      threefry2x32(kn0, kn1, 0u, rowbase + (uint32_t)j, o0, o1);
      uint32_t v = (o0 ^ o1) >> 9;
      bool cand = (!same) && (v >= newlo) && (v < lo);
      unsigned long long m = __ballot(cand);
      if (m) {
        if (cand) {
          unsigned long long key = (((unsigned long long)v << 13) | (unsigned)(8191 - j)) + 1ull;
          int ofs = __builtin_amdgcn_mbcnt_hi((uint32_t)(m >> 32),
                     __builtin_amdgcn_mbcnt_lo((uint32_t)m, 0));
          int p = count + ofs;
          if (p < CAP) buf[wave][p] = key;
        }
        count += __popcll(m);
      }
    }
    lo = newlo;
  }
  int scount = count < CAP ? count : CAP;

  // ---- once-per-row: sort the ~40 survivors to an exact top-8 ----
  unsigned long long top[8] = {0ull,0ull,0ull,0ull,0ull,0ull,0ull,0ull};
  for (int t = lane; t < scount; t += 64) {
    unsigned long long key = buf[wave][t];
    if (key > top[7]) {
      top[7] = key;
      #pragma unroll
      for (int s = 7; s > 0; --s) {
        if (top[s] > top[s - 1]) {
          unsigned long long tt = top[s - 1]; top[s - 1] = top[s]; top[s] = tt;
        }
      }
    }
  }
  // butterfly merge of sorted-desc 8-lists (bitonic)
  #pragma unroll
  for (int d = 1; d < 64; d <<= 1) {
    unsigned long long o[8];
    #pragma unroll
    for (int r = 0; r < 8; ++r) o[r] = __shfl_xor(top[r], d, 64);
    unsigned long long m[8];
    #pragma unroll
    for (int r = 0; r < 8; ++r) m[r] = u64max(top[r], o[7 - r]);
    CE_DESC(m, 0, 4) CE_DESC(m, 1, 5) CE_DESC(m, 2, 6) CE_DESC(m, 3, 7)
    CE_DESC(m, 0, 2) CE_DESC(m, 1, 3) CE_DESC(m, 4, 6) CE_DESC(m, 5, 7)
    CE_DESC(m, 0, 1) CE_DESC(m, 2, 3) CE_DESC(m, 4, 5) CE_DESC(m, 6, 7)
    #pragma unroll
    for (int r = 0; r < 8; ++r) top[r] = m[r];
  }
  // positive argmax reduce
  #pragma unroll
  for (int d = 1; d < 64; d <<= 1) best = u64max(best, __shfl_xor(best, d, 64));

  if (lane == 0) {
    pos_j[i] = best ? (8191 - (int)((best - 1ull) & 0x1FFFull)) : 0;
    #pragma unroll
    for (int r = 0; r < 8; ++r)
      neg_idx[i * 8 + r] = top[r] ? (8191 - (int)((top[r] - 1ull) & 0x1FFFull)) : r;
  }
}

// ---------------- kernel 3: 9 dots + logsumexp + mean ----------------
__global__ __launch_bounds__(256) void loss_kernel(const float* __restrict__ feat,
                                                   const float* __restrict__ inv_norm,
                                                   const int* __restrict__ pos_j,
                                                   const int* __restrict__ neg_idx,
                                                   float* __restrict__ out) {
  __shared__ float part[4];
  int wave = threadIdx.x >> 6, lane = threadIdx.x & 63;
  int i = blockIdx.x * 4 + wave;
  const float4* fi = (const float4*)(feat + (size_t)i * DD);
  float4 a0 = fi[lane], a1 = fi[lane + 64];

  int cand[9];
  cand[0] = pos_j[i];
  #pragma unroll
  for (int m = 0; m < NNEG; ++m) cand[m + 1] = neg_idx[i * 8 + m];

  // issue all 18 16B loads first (MLP), then FMA
  float4 c0[9], c1[9];
  #pragma unroll
  for (int c = 0; c < 9; ++c) {
    const float4* fc = (const float4*)(feat + (size_t)cand[c] * DD);
    c0[c] = fc[lane];
    c1[c] = fc[lane + 64];
  }
  float dots[9];
  #pragma unroll
  for (int c = 0; c < 9; ++c) {
    float s;
    s = a0.x * c0[c].x;
    s = fmaf(a0.y, c0[c].y, s); s = fmaf(a0.z, c0[c].z, s); s = fmaf(a0.w, c0[c].w, s);
    s = fmaf(a1.x, c1[c].x, s); s = fmaf(a1.y, c1[c].y, s);
    s = fmaf(a1.z, c1[c].z, s); s = fmaf(a1.w, c1[c].w, s);
    dots[c] = s;
  }
  #pragma unroll
  for (int c = 0; c < 9; ++c) {
    #pragma unroll
    for (int d = 1; d < 64; d <<= 1) dots[c] += __shfl_xor(dots[c], d, 64);
  }

  if (lane == 0) {
    float inv_i = inv_norm[i];
    float pos = dots[0] * inv_i * inv_norm[cand[0]] * 2.0f;  // /TEMPERATURE
    float t1 = -1e30f, t2 = -1e30f, t3 = -1e30f;             // top-3 of 8 negatives
    #pragma unroll
    for (int m = 0; m < NNEG; ++m) {
      float v = dots[m + 1] * inv_i * inv_norm[cand[m + 1]] * 2.0f;
      if (v > t1)      { t3 = t2; t2 = t1; t1 = v; }
      else if (v > t2) { t3 = t2; t2 = v; }
      else if (v > t3) { t3 = v; }
    }
    float mx = fmaxf(fmaxf(pos, t1), fmaxf(t2, t3));
    float lse = mx + logf(__expf(pos - mx) + __expf(t1 - mx) + __expf(t2 - mx) + __expf(t3 - mx));
    part[wave] = (lse - pos) * (1.0f / (float)BB);
  }
  __syncthreads();
  if (threadIdx.x == 0) {
    atomicAdd(out, part[0] + part[1] + part[2] + part[3]);
  }
}

// ---------------- launch ----------------
extern "C" void kernel_launch(void* const* d_in, const int* in_sizes, int n_in,
                              void* d_out, int out_size, void* d_ws, size_t ws_size,
                              hipStream_t stream) {
  const float* features = (const float*)d_in[0];
  const int* labels = (const int*)d_in[1];
  float* out = (float*)d_out;

  // workspace: inv_norm[8192] | pos_j[8192] | neg_idx[8192*8]
  float* inv_norm = (float*)d_ws;
  int* pos_j = (int*)((char*)d_ws + BB * sizeof(float));
  int* neg_idx = pos_j + BB;

  // JAX partitionable split of key(42) = (0,42)
  uint32_t kp0, kp1, kn0, kn1;
  threefry2x32(0u, 42u, 0u, 0u, kp0, kp1);
  threefry2x32(0u, 42u, 0u, 1u, kn0, kn1);

  hipMemsetAsync(d_out, 0, sizeof(float), stream);
  norm_kernel<<<BB / 4, 256, 0, stream>>>(features, inv_norm);
  select_kernel<<<BB / 4, 256, 0, stream>>>(labels, kp0, kp1, kn0, kn1, pos_j, neg_idx);
  loss_kernel<<<BB / 4, 256, 0, stream>>>(features, inv_norm, pos_j, neg_idx, out);
}

// Round 3
// 345.680 us; speedup vs baseline: 1.4610x; 1.0820x over previous
//
#include <hip/hip_runtime.h>
#include <hip/hip_bf16.h>
#include <stdint.h>

// Problem constants (fixed by reference):
#define BB 8192      // batch
#define DD 512       // feature dim
#define NNEG 8       // NUM_NEG_CANDIDATES
#define HARDK 3      // HARD_NEG_K
#define CAP 256      // per-wave candidate buffer (expected ~53 survivors)
// TEMPERATURE = 0.5 -> multiply logits by 2.0

// Negative threshold: keep top ~40 expected of ~8064 negatives.
// VT0 = 8388608 - 41984; E[count] = 8064*41984/2^23 ~= 40.4.
#define VT0 8346624u
#define VTHI 4273471488u            // VT0 << 9 (compare against full 32-bit bits)
// Positive threshold: top 10% -> E[surv] ~= 12.7 of ~127 positives;
// P(no survivor) ~ 0.9^127 ~= 1.5e-6 per row (exact rescan fallback below).
#define PTHI 3865470464u            // floor(0.9*2^23)*512 = 7549747 << 9

__host__ __device__ __forceinline__ uint32_t rotl32(uint32_t x, int r) {
#if defined(__HIP_DEVICE_COMPILE__)
  return __builtin_amdgcn_alignbit(x, x, 32 - r);  // v_alignbit_b32
#else
  return (x << r) | (x >> (32 - r));
#endif
}

// ---------------- threefry2x32 (exact JAX key schedule) ----------------
#define TF_RND(x0, x1, R) { x0 += x1; x1 = rotl32(x1, R); x1 ^= x0; }

__host__ __device__ __forceinline__ void threefry2x32(uint32_t k0, uint32_t k1,
                                                      uint32_t x0, uint32_t x1,
                                                      uint32_t& o0, uint32_t& o1) {
  uint32_t ks2 = k0 ^ k1 ^ 0x1BD11BDAu;
  x0 += k0; x1 += k1;
  TF_RND(x0, x1, 13) TF_RND(x0, x1, 15) TF_RND(x0, x1, 26) TF_RND(x0, x1, 6)
  x0 += k1; x1 += ks2 + 1u;
  TF_RND(x0, x1, 17) TF_RND(x0, x1, 29) TF_RND(x0, x1, 16) TF_RND(x0, x1, 24)
  x0 += ks2; x1 += k0 + 2u;
  TF_RND(x0, x1, 13) TF_RND(x0, x1, 15) TF_RND(x0, x1, 26) TF_RND(x0, x1, 6)
  x0 += k0; x1 += k1 + 3u;
  TF_RND(x0, x1, 17) TF_RND(x0, x1, 29) TF_RND(x0, x1, 16) TF_RND(x0, x1, 24)
  x0 += k1; x1 += ks2 + 4u;
  TF_RND(x0, x1, 13) TF_RND(x0, x1, 15) TF_RND(x0, x1, 26) TF_RND(x0, x1, 6)
  x0 += ks2; x1 += k0 + 5u;
  o0 = x0; o1 = x1;
}

// ---------------- kernel 1: inverse row norms ----------------
__global__ __launch_bounds__(256) void norm_kernel(const float* __restrict__ feat,
                                                   float* __restrict__ inv_norm) {
  int wave = threadIdx.x >> 6, lane = threadIdx.x & 63;
  int row = blockIdx.x * 4 + wave;
  const float4* fr = (const float4*)(feat + (size_t)row * DD);
  float4 a = fr[lane], b = fr[lane + 64];
  float s = a.x * a.x + a.y * a.y + a.z * a.z + a.w * a.w
          + b.x * b.x + b.y * b.y + b.z * b.z + b.w * b.w;
  #pragma unroll
  for (int d = 1; d < 64; d <<= 1) s += __shfl_xor(s, d, 64);
  if (lane == 0) inv_norm[row] = 1.0f / fmaxf(sqrtf(s), 1e-12f);
}

// ---------------- kernel 2: positive argmax + negative top-8 ----------------
// Packed selection key: (((bits>>9) << 13) | (8191 - j)) + 1, so plain u64 max
// implements (value desc, index asc) with 0 as an empty sentinel.
__device__ __forceinline__ unsigned long long u64max(unsigned long long a, unsigned long long b) {
  return a > b ? a : b;
}
#define CE_DESC(m, x, y) { if (m[x] < m[y]) { unsigned long long _t = m[x]; m[x] = m[y]; m[y] = _t; } }
#define TOP8_INSERT(top, key) \
  if ((key) > top[7]) { \
    top[7] = (key); \
    _Pragma("unroll") \
    for (int s = 7; s > 0; --s) { \
      if (top[s] > top[s - 1]) { \
        unsigned long long _tt = top[s - 1]; top[s - 1] = top[s]; top[s] = _tt; \
      } \
    } \
  }

__global__ __launch_bounds__(256) void select_kernel(const int* __restrict__ labels,
                                                     uint32_t kp0, uint32_t kp1,
                                                     uint32_t kn0, uint32_t kn1,
                                                     int* __restrict__ pos_j,
                                                     int* __restrict__ neg_idx) {
  __shared__ uint8_t slab[BB];        // labels < 64 fit in u8 (8 KB)
  __shared__ uint2 buf[4][CAP];       // per-wave survivor buffers (8 KB)
  __shared__ uint32_t cnt[4];

  int wave = threadIdx.x >> 6, lane = threadIdx.x & 63;
  int i = blockIdx.x * 4 + wave;

  // stage labels -> LDS u8
  for (int t = threadIdx.x; t < BB / 4; t += 256) {
    int4 L = ((const int4*)labels)[t];
    uchar4 c;
    c.x = (uint8_t)L.x; c.y = (uint8_t)L.y; c.z = (uint8_t)L.z; c.w = (uint8_t)L.w;
    ((uchar4*)slab)[t] = c;
  }
  if (threadIdx.x < 4) cnt[threadIdx.x] = 0u;
  __syncthreads();

  uint32_t li = slab[i];
  uint32_t rowbase = (uint32_t)i * (uint32_t)BB;

  // ---- hot loop: threefry + one threshold compare per element ----
  #pragma unroll 4
  for (int j = lane; j < BB; j += 64) {
    uint32_t lj = slab[j];
    bool same = (lj == li);
    uint32_t k0 = same ? kp0 : kn0;
    uint32_t k1 = same ? kp1 : kn1;
    uint32_t thr = same ? PTHI : VTHI;
    uint32_t o0, o1;
    threefry2x32(k0, k1, 0u, rowbase + (uint32_t)j, o0, o1);
    uint32_t bits = o0 ^ o1;
    if (bits >= thr) {                 // rare (~0.6% of lanes)
      uint32_t p = atomicAdd(&cnt[wave], 1u);
      if (p < CAP) {
        uint2 e; e.x = bits; e.y = (same ? 0x8000u : 0u) | (uint32_t)j;
        buf[wave][p] = e;
      }
    }
  }

  uint32_t count = cnt[wave];          // own-wave LDS ops: ordered, no barrier
  int scount = count < CAP ? (int)count : CAP;

  // ---- post-pass over ~53 survivors: exact top-8 negatives + positive max ----
  unsigned long long best = 0ull;
  unsigned long long top[8] = {0ull,0ull,0ull,0ull,0ull,0ull,0ull,0ull};
  for (int t = lane; t < scount; t += 64) {
    uint2 e = buf[wave][t];
    uint32_t j = e.y & 0x1FFFu;
    bool same = (e.y & 0x8000u) != 0u;
    unsigned long long key =
        (((unsigned long long)(e.x >> 9) << 13) | (unsigned)(8191u - j)) + 1ull;
    if (same) {
      if (j != (uint32_t)i) best = u64max(best, key);
    } else {
      TOP8_INSERT(top, key)
    }
  }
  // butterfly merge of sorted-desc 8-lists (bitonic)
  #pragma unroll
  for (int d = 1; d < 64; d <<= 1) {
    unsigned long long o[8];
    #pragma unroll
    for (int r = 0; r < 8; ++r) o[r] = __shfl_xor(top[r], d, 64);
    unsigned long long m[8];
    #pragma unroll
    for (int r = 0; r < 8; ++r) m[r] = u64max(top[r], o[7 - r]);
    CE_DESC(m, 0, 4) CE_DESC(m, 1, 5) CE_DESC(m, 2, 6) CE_DESC(m, 3, 7)
    CE_DESC(m, 0, 2) CE_DESC(m, 1, 3) CE_DESC(m, 4, 6) CE_DESC(m, 5, 7)
    CE_DESC(m, 0, 1) CE_DESC(m, 2, 3) CE_DESC(m, 4, 5) CE_DESC(m, 6, 7)
    #pragma unroll
    for (int r = 0; r < 8; ++r) top[r] = m[r];
  }
  #pragma unroll
  for (int d = 1; d < 64; d <<= 1) best = u64max(best, __shfl_xor(best, d, 64));

  // ---- exact fallback A: no positive survived the filter (P ~ 1e-6/row) ----
  if (best == 0ull) {                  // wave-uniform after butterfly
    for (int j = lane; j < BB; j += 64) {
      if (slab[j] == li && j != i) {
        uint32_t o0, o1;
        threefry2x32(kp0, kp1, 0u, rowbase + (uint32_t)j, o0, o1);
        unsigned long long key =
            (((unsigned long long)((o0 ^ o1) >> 9) << 13) | (unsigned)(8191 - j)) + 1ull;
        best = u64max(best, key);
      }
    }
    #pragma unroll
    for (int d = 1; d < 64; d <<= 1) best = u64max(best, __shfl_xor(best, d, 64));
  }

  // ---- exact fallback B: fewer than 8 negatives above VT0 (P ~ 1e-11/row) ----
  uint32_t lo = VT0;
  while (top[7] == 0ull && lo > 0u) {  // wave-uniform after butterfly
    uint32_t W = 8388608u - lo;
    uint32_t newlo = (W >= 1048576u) ? 0u : (8388608u - W * 8u);
    for (int j = lane; j < BB; j += 64) {
      if (slab[j] != li) {
        uint32_t o0, o1;
        threefry2x32(kn0, kn1, 0u, rowbase + (uint32_t)j, o0, o1);
        uint32_t v = (o0 ^ o1) >> 9;
        if (v >= newlo && v < lo) {
          unsigned long long key =
              (((unsigned long long)v << 13) | (unsigned)(8191 - j)) + 1ull;
          TOP8_INSERT(top, key)
        }
      }
    }
    #pragma unroll
    for (int d = 1; d < 64; d <<= 1) {
      unsigned long long o[8];
      #pragma unroll
      for (int r = 0; r < 8; ++r) o[r] = __shfl_xor(top[r], d, 64);
      unsigned long long m[8];
      #pragma unroll
      for (int r = 0; r < 8; ++r) m[r] = u64max(top[r], o[7 - r]);
      CE_DESC(m, 0, 4) CE_DESC(m, 1, 5) CE_DESC(m, 2, 6) CE_DESC(m, 3, 7)
      CE_DESC(m, 0, 2) CE_DESC(m, 1, 3) CE_DESC(m, 4, 6) CE_DESC(m, 5, 7)
      CE_DESC(m, 0, 1) CE_DESC(m, 2, 3) CE_DESC(m, 4, 5) CE_DESC(m, 6, 7)
      #pragma unroll
      for (int r = 0; r < 8; ++r) top[r] = m[r];
    }
    lo = newlo;
  }

  if (lane == 0) {
    pos_j[i] = best ? (8191 - (int)((best - 1ull) & 0x1FFFull)) : 0;
    #pragma unroll
    for (int r = 0; r < 8; ++r)
      neg_idx[i * 8 + r] = top[r] ? (8191 - (int)((top[r] - 1ull) & 0x1FFFull)) : r;
  }
}

// ---------------- kernel 3: 9 dots + logsumexp + mean ----------------
__global__ __launch_bounds__(256) void loss_kernel(const float* __restrict__ feat,
                                                   const float* __restrict__ inv_norm,
                                                   const int* __restrict__ pos_j,
                                                   const int* __restrict__ neg_idx,
                                                   float* __restrict__ out) {
  __shared__ float part[4];
  int wave = threadIdx.x >> 6, lane = threadIdx.x & 63;
  int i = blockIdx.x * 4 + wave;
  const float4* fi = (const float4*)(feat + (size_t)i * DD);
  float4 a0 = fi[lane], a1 = fi[lane + 64];

  int cand[9];
  cand[0] = pos_j[i];
  #pragma unroll
  for (int m = 0; m < NNEG; ++m) cand[m + 1] = neg_idx[i * 8 + m];

  float4 c0[9], c1[9];
  #pragma unroll
  for (int c = 0; c < 9; ++c) {
    const float4* fc = (const float4*)(feat + (size_t)cand[c] * DD);
    c0[c] = fc[lane];
    c1[c] = fc[lane + 64];
  }
  float dots[9];
  #pragma unroll
  for (int c = 0; c < 9; ++c) {
    float s;
    s = a0.x * c0[c].x;
    s = fmaf(a0.y, c0[c].y, s); s = fmaf(a0.z, c0[c].z, s); s = fmaf(a0.w, c0[c].w, s);
    s = fmaf(a1.x, c1[c].x, s); s = fmaf(a1.y, c1[c].y, s);
    s = fmaf(a1.z, c1[c].z, s); s = fmaf(a1.w, c1[c].w, s);
    dots[c] = s;
  }
  #pragma unroll
  for (int c = 0; c < 9; ++c) {
    #pragma unroll
    for (int d = 1; d < 64; d <<= 1) dots[c] += __shfl_xor(dots[c], d, 64);
  }

  if (lane == 0) {
    float inv_i = inv_norm[i];
    float pos = dots[0] * inv_i * inv_norm[cand[0]] * 2.0f;  // /TEMPERATURE
    float t1 = -1e30f, t2 = -1e30f, t3 = -1e30f;             // top-3 of 8 negatives
    #pragma unroll
    for (int m = 0; m < NNEG; ++m) {
      float v = dots[m + 1] * inv_i * inv_norm[cand[m + 1]] * 2.0f;
      if (v > t1)      { t3 = t2; t2 = t1; t1 = v; }
      else if (v > t2) { t3 = t2; t2 = v; }
      else if (v > t3) { t3 = v; }
    }
    float mx = fmaxf(fmaxf(pos, t1), fmaxf(t2, t3));
    float lse = mx + logf(__expf(pos - mx) + __expf(t1 - mx) + __expf(t2 - mx) + __expf(t3 - mx));
    part[wave] = (lse - pos) * (1.0f / (float)BB);
  }
  __syncthreads();
  if (threadIdx.x == 0) {
    atomicAdd(out, part[0] + part[1] + part[2] + part[3]);
  }
}

// ---------------- launch ----------------
extern "C" void kernel_launch(void* const* d_in, const int* in_sizes, int n_in,
                              void* d_out, int out_size, void* d_ws, size_t ws_size,
                              hipStream_t stream) {
  const float* features = (const float*)d_in[0];
  const int* labels = (const int*)d_in[1];
  float* out = (float*)d_out;

  // workspace: inv_norm[8192] | pos_j[8192] | neg_idx[8192*8]
  float* inv_norm = (float*)d_ws;
  int* pos_j = (int*)((char*)d_ws + BB * sizeof(float));
  int* neg_idx = pos_j + BB;

  // JAX partitionable split of key(42) = (0,42)
  uint32_t kp0, kp1, kn0, kn1;
  threefry2x32(0u, 42u, 0u, 0u, kp0, kp1);
  threefry2x32(0u, 42u, 0u, 1u, kn0, kn1);

  hipMemsetAsync(d_out, 0, sizeof(float), stream);
  norm_kernel<<<BB / 4, 256, 0, stream>>>(features, inv_norm);
  select_kernel<<<BB / 4, 256, 0, stream>>>(labels, kp0, kp1, kn0, kn1, pos_j, neg_idx);
  loss_kernel<<<BB / 4, 256, 0, stream>>>(features, inv_norm, pos_j, neg_idx, out);
}

// Round 4
// 254.381 us; speedup vs baseline: 1.9854x; 1.3589x over previous
//
#include <hip/hip_runtime.h>
#include <hip/hip_bf16.h>
#include <stdint.h>

// Problem constants (fixed by reference):
#define BB 8192      // batch
#define DD 512       // feature dim
#define NNEG 8       // NUM_NEG_CANDIDATES
#define CAP 256      // per-wave survivor buffer (E[survivors] ~ 41)
// TEMPERATURE = 0.5 -> multiply logits by 2.0

// Threshold in the full 32-bit bits domain: (8388608-41984)<<9.
// P(pass) = 41984/2^23 ~= 0.50%, E[count over 8192] ~= 41.
// P(fewer than 8 *diff-label* survivors) ~ Poisson(40) tail ~ 1e-11/row;
// exact widening-window fallback below regardless.
#define VTHI 4273471488u

__host__ __device__ __forceinline__ uint32_t rotl32(uint32_t x, int r) {
#if defined(__HIP_DEVICE_COMPILE__)
  return __builtin_amdgcn_alignbit(x, x, 32 - r);  // v_alignbit_b32
#else
  return (x << r) | (x >> (32 - r));
#endif
}

#define TF_RND(x0, x1, R) { x0 += x1; x1 = rotl32(x1, R); x1 ^= x0; }

// Full threefry2x32 (exact JAX schedule) — host-side key derivation.
__host__ __device__ __forceinline__ void threefry2x32(uint32_t k0, uint32_t k1,
                                                      uint32_t x0, uint32_t x1,
                                                      uint32_t& o0, uint32_t& o1) {
  uint32_t ks2 = k0 ^ k1 ^ 0x1BD11BDAu;
  x0 += k0; x1 += k1;
  TF_RND(x0, x1, 13) TF_RND(x0, x1, 15) TF_RND(x0, x1, 26) TF_RND(x0, x1, 6)
  x0 += k1; x1 += ks2 + 1u;
  TF_RND(x0, x1, 17) TF_RND(x0, x1, 29) TF_RND(x0, x1, 16) TF_RND(x0, x1, 24)
  x0 += ks2; x1 += k0 + 2u;
  TF_RND(x0, x1, 13) TF_RND(x0, x1, 15) TF_RND(x0, x1, 26) TF_RND(x0, x1, 6)
  x0 += k0; x1 += k1 + 3u;
  TF_RND(x0, x1, 17) TF_RND(x0, x1, 29) TF_RND(x0, x1, 16) TF_RND(x0, x1, 24)
  x0 += k1; x1 += ks2 + 4u;
  TF_RND(x0, x1, 13) TF_RND(x0, x1, 15) TF_RND(x0, x1, 26) TF_RND(x0, x1, 6)
  x0 += ks2; x1 += k0 + 5u;
  o0 = x0; o1 = x1;
}

// Wave-uniform-key threefry: x0 starts at 0 (hi word of the JAX counter),
// caller pre-adds k1 into x1. All key material is SGPR -> pure 3-op rounds.
__device__ __forceinline__ void tf_uniform(uint32_t k0, uint32_t k1, uint32_t x1pk,
                                           uint32_t& o0, uint32_t& o1) {
  uint32_t ks2 = k0 ^ k1 ^ 0x1BD11BDAu;   // scalar, hoisted
  uint32_t x0 = k0;                        // 0 + k0
  uint32_t x1 = x1pk;                      // ctr + k1 (pre-added)
  TF_RND(x0, x1, 13) TF_RND(x0, x1, 15) TF_RND(x0, x1, 26) TF_RND(x0, x1, 6)
  x0 += k1; x1 += ks2 + 1u;
  TF_RND(x0, x1, 17) TF_RND(x0, x1, 29) TF_RND(x0, x1, 16) TF_RND(x0, x1, 24)
  x0 += ks2; x1 += k0 + 2u;
  TF_RND(x0, x1, 13) TF_RND(x0, x1, 15) TF_RND(x0, x1, 26) TF_RND(x0, x1, 6)
  x0 += k0; x1 += k1 + 3u;
  TF_RND(x0, x1, 17) TF_RND(x0, x1, 29) TF_RND(x0, x1, 16) TF_RND(x0, x1, 24)
  x0 += k1; x1 += ks2 + 4u;
  TF_RND(x0, x1, 13) TF_RND(x0, x1, 15) TF_RND(x0, x1, 26) TF_RND(x0, x1, 6)
  x0 += ks2; x1 += k0 + 5u;
  o0 = x0; o1 = x1;
}

__device__ __forceinline__ unsigned long long u64max(unsigned long long a, unsigned long long b) {
  return a > b ? a : b;
}
#define CE_DESC(m, x, y) { if (m[x] < m[y]) { unsigned long long _t = m[x]; m[x] = m[y]; m[y] = _t; } }
#define TOP8_INSERT(top, key) \
  if ((key) > top[7]) { \
    top[7] = (key); \
    _Pragma("unroll") \
    for (int s = 7; s > 0; --s) { \
      if (top[s] > top[s - 1]) { \
        unsigned long long _tt = top[s - 1]; top[s - 1] = top[s]; top[s] = _tt; \
      } \
    } \
  }

// Bitonic merge of sorted-desc 8-lists across the wave (all lanes end with result).
__device__ __forceinline__ void wave_merge_top8(unsigned long long top[8]) {
  #pragma unroll
  for (int d = 1; d < 64; d <<= 1) {
    unsigned long long o[8];
    #pragma unroll
    for (int r = 0; r < 8; ++r) o[r] = __shfl_xor(top[r], d, 64);
    unsigned long long m[8];
    #pragma unroll
    for (int r = 0; r < 8; ++r) m[r] = u64max(top[r], o[7 - r]);
    CE_DESC(m, 0, 4) CE_DESC(m, 1, 5) CE_DESC(m, 2, 6) CE_DESC(m, 3, 7)
    CE_DESC(m, 0, 2) CE_DESC(m, 1, 3) CE_DESC(m, 4, 6) CE_DESC(m, 5, 7)
    CE_DESC(m, 0, 1) CE_DESC(m, 2, 3) CE_DESC(m, 4, 5) CE_DESC(m, 6, 7)
    #pragma unroll
    for (int r = 0; r < 8; ++r) top[r] = m[r];
  }
}

// ---------------- kernel 1: label lists (block 0) + inverse row norms ----------------
__global__ __launch_bounds__(256) void prep_kernel(const float* __restrict__ feat,
                                                   const int* __restrict__ labels,
                                                   float* __restrict__ inv_norm,
                                                   uint16_t* __restrict__ lists,
                                                   int* __restrict__ offs) {
  if (blockIdx.x == 0) {
    __shared__ uint32_t hist[64];
    __shared__ uint32_t base[64];
    int t = threadIdx.x;
    if (t < 64) hist[t] = 0u;
    __syncthreads();
    for (int e = t; e < BB; e += 256) atomicAdd(&hist[labels[e] & 63], 1u);
    __syncthreads();
    if (t == 0) {
      uint32_t s = 0;
      for (int l = 0; l < 64; ++l) { base[l] = s; offs[l] = (int)s; s += hist[l]; }
      offs[64] = (int)s;
    }
    __syncthreads();
    for (int e = t; e < BB; e += 256) {
      uint32_t p = atomicAdd(&base[labels[e] & 63], 1u);
      lists[p] = (uint16_t)e;   // order within a label is irrelevant (exact argmax key)
    }
  } else {
    int wave = threadIdx.x >> 6, lane = threadIdx.x & 63;
    int row = (blockIdx.x - 1) * 4 + wave;
    const float4* fr = (const float4*)(feat + (size_t)row * DD);
    float4 a = fr[lane], b = fr[lane + 64];
    float s = a.x * a.x + a.y * a.y + a.z * a.z + a.w * a.w
            + b.x * b.x + b.y * b.y + b.z * b.z + b.w * b.w;
    #pragma unroll
    for (int d = 1; d < 64; d <<= 1) s += __shfl_xor(s, d, 64);
    if (lane == 0) inv_norm[row] = 1.0f / fmaxf(sqrtf(s), 1e-12f);
  }
}

// ---------------- kernel 2: selection + fused loss ----------------
__global__ __launch_bounds__(256) void select_kernel(const float* __restrict__ feat,
                                                     const int* __restrict__ labels,
                                                     const float* __restrict__ inv_norm,
                                                     const uint16_t* __restrict__ lists,
                                                     const int* __restrict__ offs,
                                                     uint32_t kp0, uint32_t kp1,
                                                     uint32_t kn0, uint32_t kn1,
                                                     float* __restrict__ out) {
  __shared__ uint2 buf[4][CAP];     // per-wave survivor buffers (8 KB)
  __shared__ uint32_t cnt[4];
  __shared__ float part[4];
  int wave = threadIdx.x >> 6, lane = threadIdx.x & 63;
  int i = blockIdx.x * 4 + wave;
  if (threadIdx.x < 4) cnt[threadIdx.x] = 0u;
  __syncthreads();

  int li = labels[i];
  uint32_t rowbase = (uint32_t)i * (uint32_t)BB;

  // ---- hot loop: uniform-key threefry + 1 compare, over ALL 8192 counters ----
  uint32_t cb = rowbase + kn1 + (uint32_t)lane;
  #pragma unroll 8
  for (int it = 0; it < BB / 64; ++it) {
    uint32_t o0, o1;
    tf_uniform(kn0, kn1, cb + (uint32_t)(it * 64), o0, o1);
    uint32_t bits = o0 ^ o1;
    if (bits >= VTHI) {              // ~0.5% of lanes
      uint32_t p = atomicAdd(&cnt[wave], 1u);
      if (p < CAP) { uint2 e; e.x = bits; e.y = (uint32_t)(it * 64 + lane); buf[wave][p] = e; }
    }
  }

  // ---- positive: EXACT argmax over own-label list (~128 entries, uniform kp) ----
  unsigned long long best = 0ull;
  int beg = offs[li], end = offs[li + 1];
  for (int t = beg + lane; t < end; t += 64) {
    int j = lists[t];
    if (j != i) {
      uint32_t o0, o1;
      tf_uniform(kp0, kp1, rowbase + kp1 + (uint32_t)j, o0, o1);
      unsigned long long key =
          (((unsigned long long)((o0 ^ o1) >> 9) << 13) | (unsigned)(8191 - j)) + 1ull;
      best = u64max(best, key);
    }
  }
  #pragma unroll
  for (int d = 1; d < 64; d <<= 1) best = u64max(best, __shfl_xor(best, d, 64));

  // ---- post-pass: exact top-8 negatives from ~41 survivors (label-filtered) ----
  uint32_t count = cnt[wave];        // own-wave DS ops are ordered; no barrier needed
  unsigned long long top[8] = {0ull,0ull,0ull,0ull,0ull,0ull,0ull,0ull};
  if (count <= CAP) {
    for (int t = lane; t < (int)count; t += 64) {
      uint2 e = buf[wave][t];
      uint32_t j = e.y;
      if (labels[j] != li) {
        unsigned long long key =
            (((unsigned long long)(e.x >> 9) << 13) | (unsigned)(8191u - j)) + 1ull;
        TOP8_INSERT(top, key)
      }
    }
  } else {
    // unreachable safety (buffer overflow): exact full rescan
    for (int j = lane; j < BB; j += 64) {
      if (labels[j] != li) {
        uint32_t o0, o1;
        tf_uniform(kn0, kn1, rowbase + kn1 + (uint32_t)j, o0, o1);
        unsigned long long key =
            (((unsigned long long)((o0 ^ o1) >> 9) << 13) | (unsigned)(8191 - j)) + 1ull;
        TOP8_INSERT(top, key)
      }
    }
  }
  wave_merge_top8(top);

  // ---- exact widening-window fallback: fewer than 8 above VTHI (P ~ 1e-11/row) ----
  uint32_t hi = VTHI;
  while (top[7] == 0ull && hi != 0u) {   // wave-uniform after merge
    unsigned long long W = 0x100000000ull - (unsigned long long)hi;
    uint32_t newhi = (W * 8ull >= 0x100000000ull) ? 0u
                     : (uint32_t)(0x100000000ull - W * 8ull);
    for (int j = lane; j < BB; j += 64) {
      if (labels[j] != li) {
        uint32_t o0, o1;
        tf_uniform(kn0, kn1, rowbase + kn1 + (uint32_t)j, o0, o1);
        uint32_t bits = o0 ^ o1;
        if (bits >= newhi && bits < hi) {
          unsigned long long key =
              (((unsigned long long)(bits >> 9) << 13) | (unsigned)(8191 - j)) + 1ull;
          TOP8_INSERT(top, key)
        }
      }
    }
    wave_merge_top8(top);
    hi = newhi;
  }

  // ---- decode candidates (all lanes hold identical best/top) ----
  int cand[9];
  cand[0] = best ? (8191 - (int)((best - 1ull) & 0x1FFFull)) : 0;
  #pragma unroll
  for (int r = 0; r < NNEG; ++r)
    cand[r + 1] = top[r] ? (8191 - (int)((top[r] - 1ull) & 0x1FFFull)) : r;

  // ---- fused loss epilogue: 9 dots + logsumexp + block-reduced mean ----
  const float4* fi = (const float4*)(feat + (size_t)i * DD);
  float4 a0 = fi[lane], a1 = fi[lane + 64];
  float dots[9];
  #pragma unroll
  for (int c = 0; c < 9; ++c) {
    const float4* fc = (const float4*)(feat + (size_t)cand[c] * DD);
    float4 c0 = fc[lane], c1 = fc[lane + 64];
    float s;
    s = a0.x * c0.x;
    s = fmaf(a0.y, c0.y, s); s = fmaf(a0.z, c0.z, s); s = fmaf(a0.w, c0.w, s);
    s = fmaf(a1.x, c1.x, s); s = fmaf(a1.y, c1.y, s);
    s = fmaf(a1.z, c1.z, s); s = fmaf(a1.w, c1.w, s);
    dots[c] = s;
  }
  #pragma unroll
  for (int c = 0; c < 9; ++c) {
    #pragma unroll
    for (int d = 1; d < 64; d <<= 1) dots[c] += __shfl_xor(dots[c], d, 64);
  }

  if (lane == 0) {
    float inv_i = inv_norm[i];
    float pos = dots[0] * inv_i * inv_norm[cand[0]] * 2.0f;  // /TEMPERATURE
    float t1 = -1e30f, t2 = -1e30f, t3 = -1e30f;             // top-3 of 8 negatives
    #pragma unroll
    for (int m = 0; m < NNEG; ++m) {
      float v = dots[m + 1] * inv_i * inv_norm[cand[m + 1]] * 2.0f;
      if (v > t1)      { t3 = t2; t2 = t1; t1 = v; }
      else if (v > t2) { t3 = t2; t2 = v; }
      else if (v > t3) { t3 = v; }
    }
    float mx = fmaxf(fmaxf(pos, t1), fmaxf(t2, t3));
    float lse = mx + logf(__expf(pos - mx) + __expf(t1 - mx) + __expf(t2 - mx) + __expf(t3 - mx));
    part[wave] = (lse - pos) * (1.0f / (float)BB);
  }
  __syncthreads();
  if (threadIdx.x == 0) atomicAdd(out, part[0] + part[1] + part[2] + part[3]);
}

// ---------------- launch ----------------
extern "C" void kernel_launch(void* const* d_in, const int* in_sizes, int n_in,
                              void* d_out, int out_size, void* d_ws, size_t ws_size,
                              hipStream_t stream) {
  const float* features = (const float*)d_in[0];
  const int* labels = (const int*)d_in[1];
  float* out = (float*)d_out;

  // workspace: inv_norm f32[8192] | lists u16[8192] | offs i32[65]
  float* inv_norm = (float*)d_ws;
  uint16_t* lists = (uint16_t*)((char*)d_ws + BB * sizeof(float));
  int* offs = (int*)((char*)d_ws + BB * sizeof(float) + BB * sizeof(uint16_t));

  // JAX partitionable split of key(42) = (0,42)
  uint32_t kp0, kp1, kn0, kn1;
  threefry2x32(0u, 42u, 0u, 0u, kp0, kp1);
  threefry2x32(0u, 42u, 0u, 1u, kn0, kn1);

  hipMemsetAsync(d_out, 0, sizeof(float), stream);
  prep_kernel<<<BB / 4 + 1, 256, 0, stream>>>(features, labels, inv_norm, lists, offs);
  select_kernel<<<BB / 4, 256, 0, stream>>>(features, labels, inv_norm, lists, offs,
                                            kp0, kp1, kn0, kn1, out);
}